// Round 4
// baseline (78240.808 us; speedup 1.0000x reference)
//
#include <hip/hip_runtime.h>

#define NROWS 65536
#define DD 512
#define MSZ (DD * DD)            // 262144 floats = 1 MB
#define NS_LOOP 4                // NS iterations after the fused first one (total 5)
#define BARY_ITERS 16
#define CSPLIT 16                // covsyrk split-K
#define CCHUNK (NROWS / CSPLIT)  // 4096
#define CFAC (1.05f / 512.f)     // c = 1.05 * tr/512  (spectrum ~[0.65,1.5] -> r4 ~ 1e-8)

// ---------------- column means ----------------
__global__ __launch_bounds__(512) void colsum_kernel(const float* __restrict__ X,
                                                     const float* __restrict__ S,
                                                     float* __restrict__ sums) {
    const float* src = (blockIdx.y == 0) ? X : S;
    float* dst = sums + blockIdx.y * DD;
    int col = threadIdx.x;
    long base = (long)blockIdx.x * 256 * DD;
    float acc = 0.f;
    #pragma unroll 8
    for (int r = 0; r < 256; ++r)
        acc += src[base + (long)r * DD + col];
    atomicAdd(dst + col, acc);
}

__global__ __launch_bounds__(512) void finalize_mean_kernel(float* __restrict__ ws) {
    int t = threadIdx.x;
    const float inv_n = 1.f / (float)NROWS;
    float mc = ws[t] * inv_n;
    float ms = ws[DD + t] * inv_n;
    ws[t] = mc;
    ws[DD + t] = ms;
    ws[2 * DD + t] = 0.5f * (mc + ms);   // mu_bary
}

// ---------------- covariance: G = X^T X, 128x128 upper tiles, split-K atomics ----------------
__global__ __launch_bounds__(256) void covsyrk2_kernel(const float* __restrict__ X,
                                                       const float* __restrict__ S,
                                                       float* __restrict__ G) {
    int ta = blockIdx.x >> 2, tb = blockIdx.x & 3;
    if (ta > tb) return;                       // symmetry: upper 128-tiles only
    int a0 = ta << 7, b0 = tb << 7;
    const float* src = (blockIdx.z == 0) ? X : S;
    float* g = G + (long long)blockIdx.z * MSZ;
    long kbase = (long)blockIdx.y * CCHUNK;
    __shared__ float As[32][140];
    __shared__ float Bs[32][140];
    int t = threadIdx.x;
    int kr = t >> 5;              // 0..7
    int c4 = (t & 31) << 2;       // 0..124
    int sc = c4 + ((c4 >> 5) << 2);   // quad swizzle
    int iy = t >> 4, ix = t & 15;
    int aoff = (iy << 3) + ((iy >> 2) << 2);
    int boff = (ix << 3) + ((ix >> 2) << 2);
    float acc[8][8] = {};
    float4 pa[4], pb[4];
    #pragma unroll
    for (int p = 0; p < 4; ++p) {
        long row = (kbase + kr + p * 8) * DD;
        pa[p] = *(const float4*)(src + row + a0 + c4);
        pb[p] = *(const float4*)(src + row + b0 + c4);
    }
    for (int kb = 0; kb < CCHUNK; kb += 32) {
        __syncthreads();
        #pragma unroll
        for (int p = 0; p < 4; ++p) {
            *(float4*)&As[kr + p * 8][sc] = pa[p];
            *(float4*)&Bs[kr + p * 8][sc] = pb[p];
        }
        __syncthreads();
        if (kb + 32 < CCHUNK) {
            #pragma unroll
            for (int p = 0; p < 4; ++p) {
                long row = (kbase + kb + 32 + kr + p * 8) * DD;
                pa[p] = *(const float4*)(src + row + a0 + c4);
                pb[p] = *(const float4*)(src + row + b0 + c4);
            }
        }
        #pragma unroll 4
        for (int kk = 0; kk < 32; ++kk) {
            float a[8], bf[8];
            *(float4*)&a[0] = *(const float4*)&As[kk][aoff];
            *(float4*)&a[4] = *(const float4*)&As[kk][aoff + 4];
            *(float4*)&bf[0] = *(const float4*)&Bs[kk][boff];
            *(float4*)&bf[4] = *(const float4*)&Bs[kk][boff + 4];
            #pragma unroll
            for (int i = 0; i < 8; ++i)
                #pragma unroll
                for (int j = 0; j < 8; ++j)
                    acc[i][j] += a[i] * bf[j];
        }
    }
    #pragma unroll
    for (int i = 0; i < 8; ++i)
        #pragma unroll
        for (int j = 0; j < 8; ++j)
            atomicAdd(&g[(long)(a0 + (iy << 3) + i) * DD + b0 + (ix << 3) + j], acc[i][j]);
}

// cov = (G - n m m^T)/(n-1); mirror-read upper 128-tile; fused tr(covc) atomic into tr0
__global__ __launch_bounds__(512) void covfix_kernel(const float* __restrict__ Gt,
                                                     float* __restrict__ C,
                                                     const float* __restrict__ means,
                                                     float* __restrict__ tr0) {
    int m = blockIdx.y, i = blockIdx.x, j = threadIdx.x;
    const float* mu = means + m * DD;
    const float* g = Gt + (long)m * MSZ;
    int ii = i, jj = j;
    if ((ii >> 7) > (jj >> 7)) { int tmp = ii; ii = jj; jj = tmp; }
    float v = g[(long)ii * DD + jj];
    float val = (v - (float)NROWS * mu[i] * mu[j]) * (1.f / (float)(NROWS - 1));
    C[(long)m * MSZ + (long)i * DD + j] = val;
    if (m == 0 && i == j) atomicAdd(tr0, val);
}

// ---------------- operand transforms: 0 plain, 1 sym 0.5(V+V^T), 2 q1*B + q2*B2 ----------------
template<int OP>
__device__ __forceinline__ float4 ldA(const float* __restrict__ A, int r, int c) {
    float4 v = *(const float4*)(A + (long)r * DD + c);
    if (OP == 1) {
        v.x = 0.5f * (v.x + A[(long)(c + 0) * DD + r]);
        v.y = 0.5f * (v.y + A[(long)(c + 1) * DD + r]);
        v.z = 0.5f * (v.z + A[(long)(c + 2) * DD + r]);
        v.w = 0.5f * (v.w + A[(long)(c + 3) * DD + r]);
    }
    return v;
}
template<int OP>
__device__ __forceinline__ float4 ldB(const float* __restrict__ B, const float* __restrict__ B2,
                                      float q1, float q2, int r, int c) {
    float4 v = *(const float4*)(B + (long)r * DD + c);
    if (OP == 1) {
        v.x = 0.5f * (v.x + B[(long)(c + 0) * DD + r]);
        v.y = 0.5f * (v.y + B[(long)(c + 1) * DD + r]);
        v.z = 0.5f * (v.z + B[(long)(c + 2) * DD + r]);
        v.w = 0.5f * (v.w + B[(long)(c + 3) * DD + r]);
    } else if (OP == 2) {
        float4 w = *(const float4*)(B2 + (long)r * DD + c);
        v.x = q1 * v.x + q2 * w.x;
        v.y = q1 * v.y + q2 * w.y;
        v.z = q1 * v.z + q2 * w.z;
        v.w = q1 * v.w + q2 * w.w;
    }
    return v;
}

__device__ __forceinline__ void zrange(float* p, long long n, int fb) {
    if (!p) return;
    long long q = n >> 2;
    for (long long i = (long long)fb * 256 + threadIdx.x; i < q; i += 256ll * 256)
        *(float4*)(p + (i << 2)) = make_float4(0.f, 0.f, 0.f, 0.f);
}

// ---------------- single-dispatch split-K atomic gemm ----------------
// grid (16 tiles, ks, batch), ks = 16/batch (256 blocks total).
// C[b] += alpha_eff * A[b] @ B[b]  (+ beta*D[b] folded by slice-0 blocks).
// alpha_eff = alpha * {1 | c | 1/c}, c = CFAC * (*aslot).
// BOP==2: B-operand = q1*B + q2*B2, q_i = hq_i * sqrtf(CFAC * qslot[i]).
// trout: per-matrix trace of contribution, atomically accumulated (linear in partials).
// zp1/zp2: epilogue-zero ranges (floats, multiple of 4) -- must be disjoint from
//          this dispatch's own reads/writes (host wiring guarantees it).
template<int AOP, int BOP>
__global__ __launch_bounds__(256) void gemmk(
    const float* __restrict__ A1, const float* __restrict__ A2, long long sA1, long long sA2, int asplit,
    const float* __restrict__ B1, const float* __restrict__ B2c, long long sB1, long long sB2, int bsplit,
    const float* __restrict__ D, long long sD,
    float* __restrict__ C, long long sC,
    float alpha, float beta, const float* __restrict__ aslot, int amode,
    const float* __restrict__ qslot, float hq1, float hq2,
    float* __restrict__ trout, long long strout,
    float* __restrict__ zp1, long long zn1, float* __restrict__ zp2, long long zn2)
{
    __shared__ float As[32][132];   // As[k][i] (A transposed)
    __shared__ float Bs[32][140];   // quad-swizzled columns
    int ks = gridDim.y;
    int Ks = DD / ks;
    int b = blockIdx.z;
    int s = blockIdx.y;
    int i0 = (blockIdx.x >> 2) << 7;
    int j0 = (blockIdx.x & 3) << 7;
    int kbase = s * Ks;
    const float* A = (b < asplit) ? A1 + (long long)b * sA1 : A2 + (long long)(b - asplit) * sA2;
    const float* B = (b < bsplit) ? B1 + (long long)b * sB1 : B2c + (long long)(b - bsplit) * sB2;
    float q1 = 0.f, q2 = 0.f;
    if (BOP == 2) {
        q1 = hq1 * sqrtf(CFAC * qslot[0]);
        q2 = hq2 * sqrtf(CFAC * qslot[1]);
    }
    int t = threadIdx.x;
    int iy = t >> 4, ix = t & 15;
    int ldr = t >> 3;               // 0..31
    int ldc = (t & 7) << 2;         // 0,4,...,28
    int boff = (ix << 3) + ((ix >> 2) << 2);
    float acc[8][8] = {};
    float4 pa[4], pb[4];
    #pragma unroll
    for (int p = 0; p < 4; ++p) {
        pa[p] = ldA<AOP>(A, i0 + ldr + p * 32, kbase + ldc);
        pb[p] = ldB<BOP>(B, B2c, q1, q2, kbase + ldr, j0 + ldc + p * 32);
    }
    for (int kb = 0; kb < Ks; kb += 32) {
        __syncthreads();
        #pragma unroll
        for (int p = 0; p < 4; ++p) {
            int r = ldr + p * 32;
            As[ldc + 0][r] = pa[p].x; As[ldc + 1][r] = pa[p].y;
            As[ldc + 2][r] = pa[p].z; As[ldc + 3][r] = pa[p].w;
            int q = (ldc + p * 32) >> 2;
            *(float4*)&Bs[ldr][(q << 2) + ((q >> 3) << 2)] = pb[p];
        }
        __syncthreads();
        if (kb + 32 < Ks) {
            int k0 = kbase + kb + 32;
            #pragma unroll
            for (int p = 0; p < 4; ++p) {
                pa[p] = ldA<AOP>(A, i0 + ldr + p * 32, k0 + ldc);
                pb[p] = ldB<BOP>(B, B2c, q1, q2, k0 + ldr, j0 + ldc + p * 32);
            }
        }
        #pragma unroll 4
        for (int kk = 0; kk < 32; ++kk) {
            float a[8], bf[8];
            *(float4*)&a[0] = *(const float4*)&As[kk][iy << 3];
            *(float4*)&a[4] = *(const float4*)&As[kk][(iy << 3) + 4];
            *(float4*)&bf[0] = *(const float4*)&Bs[kk][boff];
            *(float4*)&bf[4] = *(const float4*)&Bs[kk][boff + 4];
            #pragma unroll
            for (int i = 0; i < 8; ++i)
                #pragma unroll
                for (int j = 0; j < 8; ++j)
                    acc[i][j] += a[i] * bf[j];
        }
    }
    float aeff = alpha;
    if (amode == 1) aeff *= CFAC * (*aslot);
    else if (amode == 2) aeff /= (CFAC * (*aslot));
    float* Cb = C + (long long)b * sC;
    const float* Db = D + (long long)b * sD;
    bool doD = (beta != 0.f) && (s == 0);
    bool dodiag = (trout != nullptr) && (i0 == j0) && (iy == ix);
    float tsum = 0.f;
    #pragma unroll
    for (int i = 0; i < 8; ++i) {
        long rowo = (long)(i0 + (iy << 3) + i) * DD + j0 + (ix << 3);
        #pragma unroll
        for (int j = 0; j < 8; ++j) {
            float v = aeff * acc[i][j];
            if (doD) v += beta * Db[rowo + j];
            atomicAdd(&Cb[rowo + j], v);
            if (dodiag && i == j) tsum += v;
        }
    }
    if (dodiag) atomicAdd(trout + (long long)b * strout, tsum);
    int fb = blockIdx.x + 16 * (blockIdx.y + gridDim.y * blockIdx.z);
    zrange(zp1, zn1, fb);
    zrange(zp2, zn2, fb);
}

// fused NS iteration-1: Y1 = 1.5/c*A - 0.5/c^2*G, Z1 = 1.5I - 0.5/c*A; c = CFAC*tr
__global__ __launch_bounds__(256) void nsinit_kernel(
    const float* __restrict__ Ab, long long sA, int symA,
    const float* __restrict__ Gb, long long sG,
    float* __restrict__ Yb, float* __restrict__ Zb, long long sYZ,
    const float* __restrict__ trb, int trstride)
{
    int r = blockIdx.y;
    float c = CFAC * trb[r * trstride];
    float ic = 1.f / c;
    long idx = ((long)blockIdx.x * 256 + threadIdx.x) << 2;
    int row = (int)(idx >> 9);
    int col = (int)(idx & 511);
    const float* A = Ab + (long long)r * sA;
    float4 a = *(const float4*)(A + idx);
    if (symA) {
        a.x = 0.5f * (a.x + A[(long)(col + 0) * DD + row]);
        a.y = 0.5f * (a.y + A[(long)(col + 1) * DD + row]);
        a.z = 0.5f * (a.z + A[(long)(col + 2) * DD + row]);
        a.w = 0.5f * (a.w + A[(long)(col + 3) * DD + row]);
    }
    float4 g = *(const float4*)(Gb + (long long)r * sG + idx);
    float f15 = 1.5f * ic, f05 = -0.5f * ic * ic, nh = -0.5f * ic;
    float4 y;
    y.x = f15 * a.x + f05 * g.x; y.y = f15 * a.y + f05 * g.y;
    y.z = f15 * a.z + f05 * g.z; y.w = f15 * a.w + f05 * g.w;
    *(float4*)(Yb + (long long)r * sYZ + idx) = y;
    float4 z;
    z.x = nh * a.x; z.y = nh * a.y; z.z = nh * a.z; z.w = nh * a.w;
    int dq = row - col;
    if (dq >= 0 && dq < 4) (&z.x)[dq] += 1.5f;
    *(float4*)(Zb + (long long)r * sYZ + idx) = z;
}

// bias_j = mu_b[j] - sum_k mu_c[k]*M[j][k]
__global__ __launch_bounds__(64) void bias_kernel(const float* __restrict__ M,
                                                  const float* __restrict__ means,
                                                  float* __restrict__ bias) {
    int j = blockIdx.x;
    int lane = threadIdx.x;
    const float* mu_c = means;
    const float* mu_b = means + 2 * DD;
    float p = 0.f;
    for (int k = lane; k < DD; k += 64)
        p += mu_c[k] * M[(long)j * DD + k];
    #pragma unroll
    for (int off = 32; off > 0; off >>= 1)
        p += __shfl_down(p, off, 64);
    if (lane == 0) bias[j] = mu_b[j] - p;
}

// out = X @ M^T + bias; 128x128 tiles, 8x8 micro.
__global__ __launch_bounds__(256) void outgemm2_kernel(const float* __restrict__ X,
                                                       const float* __restrict__ M,
                                                       const float* __restrict__ bias,
                                                       float* __restrict__ out) {
    int j0 = blockIdx.x << 7;
    int i0 = blockIdx.y << 7;
    __shared__ float As[32][132];
    __shared__ float Bs[32][140];
    int t = threadIdx.x;
    int iy = t >> 4, ix = t & 15;
    int ldr = t >> 3;
    int ldc = (t & 7) << 2;
    int boff = (ix << 3) + ((ix >> 2) << 2);
    float acc[8][8] = {};
    float4 pa[4], pb[4];
    #pragma unroll
    for (int p = 0; p < 4; ++p) {
        pa[p] = *(const float4*)(X + (long)(i0 + ldr + p * 32) * DD + ldc);
        pb[p] = *(const float4*)(M + (long)(j0 + ldr + p * 32) * DD + ldc);
    }
    for (int kb = 0; kb < DD; kb += 32) {
        __syncthreads();
        #pragma unroll
        for (int p = 0; p < 4; ++p) {
            int r = ldr + p * 32;
            As[ldc + 0][r] = pa[p].x; As[ldc + 1][r] = pa[p].y;
            As[ldc + 2][r] = pa[p].z; As[ldc + 3][r] = pa[p].w;
            int q = r >> 2;
            int bc = (q << 2) + ((q >> 3) << 2) + (r & 3);
            Bs[ldc + 0][bc] = pb[p].x; Bs[ldc + 1][bc] = pb[p].y;
            Bs[ldc + 2][bc] = pb[p].z; Bs[ldc + 3][bc] = pb[p].w;
        }
        __syncthreads();
        if (kb + 32 < DD) {
            #pragma unroll
            for (int p = 0; p < 4; ++p) {
                pa[p] = *(const float4*)(X + (long)(i0 + ldr + p * 32) * DD + kb + 32 + ldc);
                pb[p] = *(const float4*)(M + (long)(j0 + ldr + p * 32) * DD + kb + 32 + ldc);
            }
        }
        #pragma unroll 4
        for (int kk = 0; kk < 32; ++kk) {
            float a[8], bf[8];
            *(float4*)&a[0] = *(const float4*)&As[kk][iy << 3];
            *(float4*)&a[4] = *(const float4*)&As[kk][(iy << 3) + 4];
            *(float4*)&bf[0] = *(const float4*)&Bs[kk][boff];
            *(float4*)&bf[4] = *(const float4*)&Bs[kk][boff + 4];
            #pragma unroll
            for (int i = 0; i < 8; ++i)
                #pragma unroll
                for (int j = 0; j < 8; ++j)
                    acc[i][j] += a[i] * bf[j];
        }
    }
    float4 bv0 = *(const float4*)(bias + j0 + (ix << 3));
    float4 bv1 = *(const float4*)(bias + j0 + (ix << 3) + 4);
    #pragma unroll
    for (int i = 0; i < 8; ++i) {
        long off = (long)(i0 + (iy << 3) + i) * DD + j0 + (ix << 3);
        float4 v0 = *(float4*)&acc[i][0];
        float4 v1 = *(float4*)&acc[i][4];
        v0.x += bv0.x; v0.y += bv0.y; v0.z += bv0.z; v0.w += bv0.w;
        v1.x += bv1.x; v1.y += bv1.y; v1.z += bv1.z; v1.w += bv1.w;
        *(float4*)(out + off) = v0;
        *(float4*)(out + off + 4) = v1;
    }
}

// ---------------- host orchestration ----------------
typedef void (*GKfn)(const float*, const float*, long long, long long, int,
                     const float*, const float*, long long, long long, int,
                     const float*, long long, float*, long long,
                     float, float, const float*, int,
                     const float*, float, float,
                     float*, long long,
                     float*, long long, float*, long long);

extern "C" void kernel_launch(void* const* d_in, const int* in_sizes, int n_in,
                              void* d_out, int out_size, void* d_ws, size_t ws_size,
                              hipStream_t stream) {
    const float* X = (const float*)d_in[0];
    const float* S = (const float*)d_in[1];
    float* out = (float*)d_out;
    float* ws = (float*)d_ws;

    // ws: [0,512) mean_c, [512,1024) mean_s, [1024,1536) mu_b, [1536,2048) bias
    //     2048..2064 trSig[17], 2068..2072 trMid[2]+pad
    // MATS = ws+4096 (17 slots, ~17MB): 0 covc, 1 covs, 2 Sig0, 3 Sig1,
    //   4 Y, 5 Z (pairA), 6 Wa, 7 Wb, 8,9 pairB, 10 G, 11 P0, 12 P1,
    //   13 mid0, 14 mid1, 15 U, 16 M
    // d_out scratch (dead until outgemm): 0 G2(2), 2 pairA2(4), 6 pairB2(4),
    //   10 W2a(2), 12 W2b(2), 14 covpool(2)  [units of MSZ]
    float* trSig = ws + 2048;
    float* trMid = ws + 2068;
    float* bias  = ws + 1536;
    float* MATS  = ws + 4096;
    auto m_ = [&](int i) { return MATS + (long long)i * MSZ; };
    float* covc = m_(0);
    float* Sg[2] = { m_(2), m_(3) };
    float* Y    = m_(4);      // pairA base (Y=4, Z=5)
    float* Z    = m_(5);
    float* Wa   = m_(6);
    float* Wb   = m_(7);
    float* pB   = m_(8);      // pairB base (8,9)
    float* G    = m_(10);
    float* P01  = m_(11);
    float* mid01= m_(13);
    float* U    = m_(15);
    float* Mx   = m_(16);
    float* sc   = out;
    float* G2   = sc;
    float* pA2  = sc + 2ll * MSZ;
    float* pB2  = sc + 6ll * MSZ;
    float* W2a  = sc + 10ll * MSZ;
    float* W2b  = sc + 12ll * MSZ;
    float* covpool = sc + 14ll * MSZ;

    GKfn g00 = gemmk<0, 0>;
    GKfn g11 = gemmk<1, 1>;
    GKfn g01 = gemmk<0, 1>;
    GKfn g02 = gemmk<0, 2>;

    auto GEMM = [&](GKfn kf, int batch,
                    const float* A1, const float* A2, long long sA1, long long sA2, int asplit,
                    const float* B1, const float* B2, long long sB1, long long sB2, int bsplit,
                    const float* D, long long sD, float* C, long long sC,
                    float alpha, float beta, const float* aslot, int amode,
                    const float* qslot, float hq1, float hq2,
                    float* trout, long long strout,
                    float* zp1, long long zn1, float* zp2, long long zn2) {
        int ks = 16 / batch;
        kf<<<dim3(16, ks, batch), 256, 0, stream>>>(A1, A2, sA1, sA2, asplit,
            B1, B2, sB1, sB2, bsplit, D, sD, C, sC, alpha, beta, aslot, amode,
            qslot, hq1, hq2, trout, strout, zp1, zn1, zp2, zn2);
    };

    // replay-safe init: zero means/traces + all 17 MATS slots; zero d_out scratch (16 MB)
    hipMemsetAsync(ws, 0, (4096 + 17ll * MSZ) * sizeof(float), stream);
    hipMemsetAsync(sc, 0, 16ll * MSZ * sizeof(float), stream);

    colsum_kernel<<<dim3(256, 2), 512, 0, stream>>>(X, S, ws);
    finalize_mean_kernel<<<1, 512, 0, stream>>>(ws);
    covsyrk2_kernel<<<dim3(16, CSPLIT, 2), 256, 0, stream>>>(X, S, covpool);
    covfix_kernel<<<dim3(512, 2), 512, 0, stream>>>(covpool, covc, ws, trSig);

    // NS tail loop (4 iters). Zero-rules: Wg_k zeroes {W_other, pair_other};
    // last upd zeroes the caller's one-off (disjoint from its own buffers).
    auto nsloop = [&](float* pA_, float* pB_, float* Wa_, float* Wb_, int nb,
                      float* lastZ, long long lastN) {
        for (int k = 0; k < NS_LOOP; ++k) {
            float* cur = (k & 1) ? pB_ : pA_;
            float* oth = (k & 1) ? pA_ : pB_;
            float* Wx  = (k & 1) ? Wb_ : Wa_;
            float* Wo  = (k & 1) ? Wa_ : Wb_;
            // W_b = Z_b @ Y_b
            GEMM(g00, nb, cur + (long long)nb * MSZ, nullptr, MSZ, 0, nb,
                 cur, nullptr, MSZ, 0, nb,
                 nullptr, 0, Wx, MSZ, 1.f, 0.f, nullptr, 0,
                 nullptr, 0.f, 0.f, nullptr, 0,
                 Wo, (long long)nb * MSZ, oth, 2ll * nb * MSZ);
            // batch 2nb: b<nb: Yn = 1.5Y - 0.5*Y@W ; b>=nb: Zn = 1.5Z - 0.5*W@Z
            bool last = (k == NS_LOOP - 1);
            GEMM(g00, 2 * nb, cur, Wx, MSZ, MSZ, nb,
                 Wx, cur + (long long)nb * MSZ, MSZ, MSZ, nb,
                 cur, MSZ, oth, MSZ, -0.5f, 1.5f, nullptr, 0,
                 nullptr, 0.f, 0.f, nullptr, 0,
                 last ? lastZ : nullptr, last ? lastN : 0, nullptr, 0);
        }
    };

    for (int t = 0; t < BARY_ITERS; ++t) {
        const float* Sread = (t == 0) ? covc : Sg[t & 1];
        float* Snxt = Sg[1 - (t & 1)];
        // G = sym(S)@sym(S); epi-zero trMid
        GEMM(g11, 1, Sread, nullptr, 0, 0, 1, Sread, nullptr, 0, 0, 1,
             nullptr, 0, G, 0, 1.f, 0.f, nullptr, 0, nullptr, 0.f, 0.f,
             nullptr, 0, trMid, 4, nullptr, 0);
        nsinit_kernel<<<dim3(256, 1), 256, 0, stream>>>(Sread, 0, 1, G, 0, Y, Z, MSZ, trSig + t, 0);
        nsloop(Y, pB, Wa, Wb, 1, P01, 2ll * MSZ);            // -> Ysig=m4, Zsig=m5
        // P_j = Ysig @ cov_j ; epi-zero mid01
        GEMM(g00, 2, Y, nullptr, 0, 0, 2, covc, nullptr, MSZ, 0, 2,
             nullptr, 0, P01, MSZ, 1.f, 0.f, nullptr, 0, nullptr, 0.f, 0.f,
             nullptr, 0, mid01, 2ll * MSZ, nullptr, 0);
        // mid_j = c0 * P_j @ Ysig (+trace -> trMid); epi-zero G2
        GEMM(g00, 2, P01, nullptr, MSZ, 0, 2, Y, nullptr, 0, 0, 2,
             nullptr, 0, mid01, MSZ, 1.f, 0.f, trSig + t, 1, nullptr, 0.f, 0.f,
             trMid, 1, G2, 2ll * MSZ, nullptr, 0);
        // G2_j = mid_j @ mid_j
        GEMM(g00, 2, mid01, nullptr, MSZ, 0, 2, mid01, nullptr, MSZ, 0, 2,
             nullptr, 0, G2, MSZ, 1.f, 0.f, nullptr, 0, nullptr, 0.f, 0.f,
             nullptr, 0, nullptr, 0, nullptr, 0);
        nsinit_kernel<<<dim3(256, 2), 256, 0, stream>>>(mid01, MSZ, 0, G2, MSZ,
                                                        pA2, pA2 + 2ll * MSZ, MSZ, trMid, 1);
        nsloop(pA2, pB2, W2a, W2b, 2, U, MSZ);               // -> Yb in pA2[0],[1]
        // U = Zsig @ (0.5*sqrt(c1)*Yb0 + 0.5*sqrt(c2)*Yb1); epi-zero Snxt
        GEMM(g02, 1, Z, nullptr, 0, 0, 1, pA2, pA2 + MSZ, 0, 0, 1,
             nullptr, 0, U, 0, 1.f, 0.f, nullptr, 0, trMid, 0.5f, 0.5f,
             nullptr, 0, Snxt, MSZ, nullptr, 0);
        // Snxt = (1/c0) * U @ Zsig (+trace -> trSig[t+1]); epi-zero G
        GEMM(g00, 1, U, nullptr, 0, 0, 1, Z, nullptr, 0, 0, 1,
             nullptr, 0, Snxt, 0, 1.f, 0.f, trSig + t, 2, nullptr, 0.f, 0.f,
             trSig + t + 1, 0, G, MSZ, nullptr, 0);
    }

    // ---- final transform: M = covc^{-1/2} (covc^{1/2} Sigma covc^{1/2})^{1/2} covc^{-1/2} ----
    const float* SigF = Sg[0];   // V(15) wrote Sg[0]
    GEMM(g11, 1, covc, nullptr, 0, 0, 1, covc, nullptr, 0, 0, 1,
         nullptr, 0, G, 0, 1.f, 0.f, nullptr, 0, nullptr, 0.f, 0.f,
         nullptr, 0, trMid, 4, nullptr, 0);
    nsinit_kernel<<<dim3(256, 1), 256, 0, stream>>>(covc, 0, 1, G, 0, Y, Z, MSZ, trSig, 0);
    nsloop(Y, pB, Wa, Wb, 1, P01, 2ll * MSZ);
    // P = Ysig @ sym(SigF); epi-zero mid01
    GEMM(g01, 1, Y, nullptr, 0, 0, 1, SigF, nullptr, 0, 0, 1,
         nullptr, 0, P01, 0, 1.f, 0.f, nullptr, 0, nullptr, 0.f, 0.f,
         nullptr, 0, mid01, 2ll * MSZ, nullptr, 0);
    // midF = c0 * P @ Ysig (+trace -> trMid[0]); epi-zero G2
    GEMM(g00, 1, P01, nullptr, 0, 0, 1, Y, nullptr, 0, 0, 1,
         nullptr, 0, mid01, 0, 1.f, 0.f, trSig, 1, nullptr, 0.f, 0.f,
         trMid, 1, G2, 2ll * MSZ, nullptr, 0);
    GEMM(g00, 1, mid01, nullptr, 0, 0, 1, mid01, nullptr, 0, 0, 1,
         nullptr, 0, G2, 0, 1.f, 0.f, nullptr, 0, nullptr, 0.f, 0.f,
         nullptr, 0, nullptr, 0, nullptr, 0);
    nsinit_kernel<<<dim3(256, 1), 256, 0, stream>>>(mid01, 0, 0, G2, 0,
                                                    pA2, pA2 + MSZ, 0, trMid, 1);
    nsloop(pA2, pB2, W2a, W2b, 1, U, MSZ);                   // -> Yb in pA2[0]
    // U = sqrt(c1) * Zsig @ Yb
    GEMM(g02, 1, Z, nullptr, 0, 0, 1, pA2, pA2, 0, 0, 1,
         nullptr, 0, U, 0, 1.f, 0.f, nullptr, 0, trMid, 1.f, 0.f,
         nullptr, 0, nullptr, 0, nullptr, 0);
    // M = (1/c0) * U @ Zsig
    GEMM(g00, 1, U, nullptr, 0, 0, 1, Z, nullptr, 0, 0, 1,
         nullptr, 0, Mx, 0, 1.f, 0.f, trSig, 2, nullptr, 0.f, 0.f,
         nullptr, 0, nullptr, 0, nullptr, 0);
    bias_kernel<<<512, 64, 0, stream>>>(Mx, ws, bias);
    outgemm2_kernel<<<dim3(4, 512), 256, 0, stream>>>(X, Mx, bias, out);
}

// Round 5
// 13135.353 us; speedup vs baseline: 5.9565x; 5.9565x over previous
//
#include <hip/hip_runtime.h>

#define NROWS 65536
#define DD 512
#define MSZ (DD * DD)            // 262144 floats = 1 MB
#define BARY_ITERS 16
#define CSPLIT 16                // covsyrk split-K
#define CCHUNK (NROWS / CSPLIT)  // 4096
#define CFAC (1.05f / 512.f)     // c = 1.05 * tr/512
#define NS_SIG 3                 // loop iters (4 total) for Sigma/covc (MP-tight spectrum)
#define NS_MID 4                 // loop iters (5 total) for mid matrices

// ---------------- column means ----------------
__global__ __launch_bounds__(512) void colsum_kernel(const float* __restrict__ X,
                                                     const float* __restrict__ S,
                                                     float* __restrict__ sums) {
    const float* src = (blockIdx.y == 0) ? X : S;
    float* dst = sums + blockIdx.y * DD;
    int col = threadIdx.x;
    long base = (long)blockIdx.x * 256 * DD;
    float acc = 0.f;
    #pragma unroll 8
    for (int r = 0; r < 256; ++r)
        acc += src[base + (long)r * DD + col];
    atomicAdd(dst + col, acc);
}

__global__ __launch_bounds__(512) void finalize_mean_kernel(float* __restrict__ ws) {
    int t = threadIdx.x;
    const float inv_n = 1.f / (float)NROWS;
    float mc = ws[t] * inv_n;
    float ms = ws[DD + t] * inv_n;
    ws[t] = mc;
    ws[DD + t] = ms;
    ws[2 * DD + t] = 0.5f * (mc + ms);   // mu_bary
}

// ---------------- covariance: G = X^T X, 128x128 upper tiles, split-K atomics ----------------
__global__ __launch_bounds__(256) void covsyrk2_kernel(const float* __restrict__ X,
                                                       const float* __restrict__ S,
                                                       float* __restrict__ G) {
    int ta = blockIdx.x >> 2, tb = blockIdx.x & 3;
    if (ta > tb) return;                       // symmetry: upper 128-tiles only
    int a0 = ta << 7, b0 = tb << 7;
    const float* src = (blockIdx.z == 0) ? X : S;
    float* g = G + (long long)blockIdx.z * MSZ;
    long kbase = (long)blockIdx.y * CCHUNK;
    __shared__ float As[32][140];
    __shared__ float Bs[32][140];
    int t = threadIdx.x;
    int kr = t >> 5;              // 0..7
    int c4 = (t & 31) << 2;       // 0..124
    int sc = c4 + ((c4 >> 5) << 2);   // quad swizzle
    int iy = t >> 4, ix = t & 15;
    int aoff = (iy << 3) + ((iy >> 2) << 2);
    int boff = (ix << 3) + ((ix >> 2) << 2);
    float acc[8][8] = {};
    float4 pa[4], pb[4];
    #pragma unroll
    for (int p = 0; p < 4; ++p) {
        long row = (kbase + kr + p * 8) * DD;
        pa[p] = *(const float4*)(src + row + a0 + c4);
        pb[p] = *(const float4*)(src + row + b0 + c4);
    }
    for (int kb = 0; kb < CCHUNK; kb += 32) {
        __syncthreads();
        #pragma unroll
        for (int p = 0; p < 4; ++p) {
            *(float4*)&As[kr + p * 8][sc] = pa[p];
            *(float4*)&Bs[kr + p * 8][sc] = pb[p];
        }
        __syncthreads();
        if (kb + 32 < CCHUNK) {
            #pragma unroll
            for (int p = 0; p < 4; ++p) {
                long row = (kbase + kb + 32 + kr + p * 8) * DD;
                pa[p] = *(const float4*)(src + row + a0 + c4);
                pb[p] = *(const float4*)(src + row + b0 + c4);
            }
        }
        #pragma unroll 4
        for (int kk = 0; kk < 32; ++kk) {
            float a[8], bf[8];
            *(float4*)&a[0] = *(const float4*)&As[kk][aoff];
            *(float4*)&a[4] = *(const float4*)&As[kk][aoff + 4];
            *(float4*)&bf[0] = *(const float4*)&Bs[kk][boff];
            *(float4*)&bf[4] = *(const float4*)&Bs[kk][boff + 4];
            #pragma unroll
            for (int i = 0; i < 8; ++i)
                #pragma unroll
                for (int j = 0; j < 8; ++j)
                    acc[i][j] += a[i] * bf[j];
        }
    }
    #pragma unroll
    for (int i = 0; i < 8; ++i)
        #pragma unroll
        for (int j = 0; j < 8; ++j)
            atomicAdd(&g[(long)(a0 + (iy << 3) + i) * DD + b0 + (ix << 3) + j], acc[i][j]);
}

// cov = (G - n m m^T)/(n-1); mirror-read upper 128-tile; fused tr(covc) atomic into tr0
__global__ __launch_bounds__(512) void covfix_kernel(const float* __restrict__ Gt,
                                                     float* __restrict__ C,
                                                     const float* __restrict__ means,
                                                     float* __restrict__ tr0) {
    int m = blockIdx.y, i = blockIdx.x, j = threadIdx.x;
    const float* mu = means + m * DD;
    const float* g = Gt + (long)m * MSZ;
    int ii = i, jj = j;
    if ((ii >> 7) > (jj >> 7)) { int tmp = ii; ii = jj; jj = tmp; }
    float v = g[(long)ii * DD + jj];
    float val = (v - (float)NROWS * mu[i] * mu[j]) * (1.f / (float)(NROWS - 1));
    C[(long)m * MSZ + (long)i * DD + j] = val;
    if (m == 0 && i == j) atomicAdd(tr0, val);
}

// ---------------- operand transforms: 0 plain, 1 sym 0.5(V+V^T), 2 q1*B + q2*B2 ----------------
template<int OP>
__device__ __forceinline__ float4 ldA(const float* __restrict__ A, int r, int c) {
    float4 v = *(const float4*)(A + (long)r * DD + c);
    if (OP == 1) {
        v.x = 0.5f * (v.x + A[(long)(c + 0) * DD + r]);
        v.y = 0.5f * (v.y + A[(long)(c + 1) * DD + r]);
        v.z = 0.5f * (v.z + A[(long)(c + 2) * DD + r]);
        v.w = 0.5f * (v.w + A[(long)(c + 3) * DD + r]);
    }
    return v;
}
template<int OP>
__device__ __forceinline__ float4 ldB(const float* __restrict__ B, const float* __restrict__ B2,
                                      float q1, float q2, int r, int c) {
    float4 v = *(const float4*)(B + (long)r * DD + c);
    if (OP == 1) {
        v.x = 0.5f * (v.x + B[(long)(c + 0) * DD + r]);
        v.y = 0.5f * (v.y + B[(long)(c + 1) * DD + r]);
        v.z = 0.5f * (v.z + B[(long)(c + 2) * DD + r]);
        v.w = 0.5f * (v.w + B[(long)(c + 3) * DD + r]);
    } else if (OP == 2) {
        float4 w = *(const float4*)(B2 + (long)r * DD + c);
        v.x = q1 * v.x + q2 * w.x;
        v.y = q1 * v.y + q2 * w.y;
        v.z = q1 * v.z + q2 * w.z;
        v.w = q1 * v.w + q2 * w.w;
    }
    return v;
}

// ---------------- split-K gemm to pool: 128x64 tiles, grid (32, ks, batch), ks*batch=16 ----------
// pool slice (b*ks+s) <- A_b[:, kslice] @ B_b[kslice, :] partials (overwrite, no zero needed)
template<int AOP, int BOP>
__global__ __launch_bounds__(256) void mmk(
    const float* __restrict__ A1, const float* __restrict__ A2, long long sA1, long long sA2, int asplit,
    const float* __restrict__ B1, const float* __restrict__ B2c, long long sB1, long long sB2, int bsplit,
    const float* __restrict__ qslot, float hq1, float hq2,
    float* __restrict__ pool)
{
    __shared__ float As[32][132];   // As[k][i] (A transposed)
    __shared__ float Bs[32][68];    // Bs[k][j]
    int ks = gridDim.y;
    int Ks = DD / ks;
    int b = blockIdx.z, s = blockIdx.y, tile = blockIdx.x;
    int i0 = (tile >> 3) << 7;      // 4 i-tiles of 128
    int j0 = (tile & 7) << 6;       // 8 j-tiles of 64
    int kbase = s * Ks;
    const float* A = (b < asplit) ? A1 + (long long)b * sA1 : A2 + (long long)(b - asplit) * sA2;
    const float* B = (b < bsplit) ? B1 + (long long)b * sB1 : B2c + (long long)(b - bsplit) * sB2;
    float q1 = 0.f, q2 = 0.f;
    if (BOP == 2) {
        q1 = hq1 * sqrtf(CFAC * qslot[0]);
        q2 = hq2 * sqrtf(CFAC * qslot[1]);
    }
    int t = threadIdx.x;
    int iy = t >> 4, ix = t & 15;
    int ldr = t >> 3;               // 0..31 (A row within 32-row group)
    int ldc = (t & 7) << 2;         // 0..28 (A k offset)
    int kr2 = t >> 4;               // 0..15 (B k row)
    int jc  = (t & 15) << 2;        // 0..60 (B col)
    float acc[8][4] = {};
    float4 pa[4], pb[2];
    #pragma unroll
    for (int p = 0; p < 4; ++p)
        pa[p] = ldA<AOP>(A, i0 + ldr + p * 32, kbase + ldc);
    #pragma unroll
    for (int p = 0; p < 2; ++p)
        pb[p] = ldB<BOP>(B, B2c, q1, q2, kbase + kr2 + p * 16, j0 + jc);
    for (int kb = 0; kb < Ks; kb += 32) {
        __syncthreads();
        #pragma unroll
        for (int p = 0; p < 4; ++p) {
            int r = ldr + p * 32;
            As[ldc + 0][r] = pa[p].x; As[ldc + 1][r] = pa[p].y;
            As[ldc + 2][r] = pa[p].z; As[ldc + 3][r] = pa[p].w;
        }
        #pragma unroll
        for (int p = 0; p < 2; ++p)
            *(float4*)&Bs[kr2 + p * 16][jc] = pb[p];
        __syncthreads();
        if (kb + 32 < Ks) {
            int k0 = kbase + kb + 32;
            #pragma unroll
            for (int p = 0; p < 4; ++p)
                pa[p] = ldA<AOP>(A, i0 + ldr + p * 32, k0 + ldc);
            #pragma unroll
            for (int p = 0; p < 2; ++p)
                pb[p] = ldB<BOP>(B, B2c, q1, q2, k0 + kr2 + p * 16, j0 + jc);
        }
        #pragma unroll 4
        for (int kk = 0; kk < 32; ++kk) {
            float a[8], bf[4];
            *(float4*)&a[0] = *(const float4*)&As[kk][iy << 3];
            *(float4*)&a[4] = *(const float4*)&As[kk][(iy << 3) + 4];
            *(float4*)&bf[0] = *(const float4*)&Bs[kk][ix << 2];
            #pragma unroll
            for (int i = 0; i < 8; ++i)
                #pragma unroll
                for (int j = 0; j < 4; ++j)
                    acc[i][j] += a[i] * bf[j];
        }
    }
    float* P = pool + (long long)(b * ks + s) * MSZ;
    #pragma unroll
    for (int i = 0; i < 8; ++i)
        *(float4*)(P + (long)(i0 + (iy << 3) + i) * DD + j0 + (ix << 2)) = *(float4*)&acc[i][0];
}

// C_b = alpha_eff * sum_s pool[b*KS+s] + beta*D_b; alpha_eff = alpha * {1|c|1/c}, c = CFAC*aslot.
// trout: atomicAdd per-matrix trace of the written C.
template<int KS>
__global__ __launch_bounds__(256) void reducek(
    const float* __restrict__ pool,
    const float* __restrict__ D1, const float* __restrict__ D2, long long sD1, long long sD2, int dsplit,
    float* __restrict__ C1, float* __restrict__ C2, long long sC1, long long sC2, int csplit,
    float alpha, float beta, const float* __restrict__ aslot, int amode,
    float* __restrict__ trout, long long strout)
{
    int b = blockIdx.y;
    long idx = ((long)blockIdx.x * 256 + threadIdx.x) << 2;
    const float* P = pool + (long long)b * KS * MSZ + idx;
    float4 a = *(const float4*)P;
    #pragma unroll
    for (int k = 1; k < KS; ++k) {
        float4 v = *(const float4*)(P + (long long)k * MSZ);
        a.x += v.x; a.y += v.y; a.z += v.z; a.w += v.w;
    }
    float aeff = alpha;
    if (amode == 1) aeff *= CFAC * (*aslot);
    else if (amode == 2) aeff /= (CFAC * (*aslot));
    a.x *= aeff; a.y *= aeff; a.z *= aeff; a.w *= aeff;
    if (beta != 0.f) {
        const float* Db = (b < dsplit) ? D1 + (long long)b * sD1 : D2 + (long long)(b - dsplit) * sD2;
        float4 d = *(const float4*)(Db + idx);
        a.x += beta * d.x; a.y += beta * d.y; a.z += beta * d.z; a.w += beta * d.w;
    }
    float* Cb = (b < csplit) ? C1 + (long long)b * sC1 : C2 + (long long)(b - csplit) * sC2;
    *(float4*)(Cb + idx) = a;
    if (trout) {
        int row = (int)(idx >> 9), col = (int)(idx & 511);
        int dq = row - col;
        if (dq >= 0 && dq < 4) atomicAdd(trout + (long long)b * strout, (&a.x)[dq]);
    }
}

// fused G-reduce + NS init: G = sum pool; Y1 = 1.5/c*A - 0.5/c^2*G; Z1 = 1.5I - 0.5/c*A
template<int KS>
__global__ __launch_bounds__(256) void nsinitk(
    const float* __restrict__ pool,
    const float* __restrict__ Ab, long long sA, int symA,
    float* __restrict__ Yb, float* __restrict__ Zb, long long sYZ,
    const float* __restrict__ trb, int trstride)
{
    int r = blockIdx.y;
    float c = CFAC * trb[r * trstride];
    float ic = 1.f / c;
    long idx = ((long)blockIdx.x * 256 + threadIdx.x) << 2;
    int row = (int)(idx >> 9), col = (int)(idx & 511);
    const float* A = Ab + (long long)r * sA;
    float4 a = *(const float4*)(A + idx);
    if (symA) {
        a.x = 0.5f * (a.x + A[(long)(col + 0) * DD + row]);
        a.y = 0.5f * (a.y + A[(long)(col + 1) * DD + row]);
        a.z = 0.5f * (a.z + A[(long)(col + 2) * DD + row]);
        a.w = 0.5f * (a.w + A[(long)(col + 3) * DD + row]);
    }
    const float* P = pool + (long long)r * KS * MSZ + idx;
    float4 g = *(const float4*)P;
    #pragma unroll
    for (int k = 1; k < KS; ++k) {
        float4 v = *(const float4*)(P + (long long)k * MSZ);
        g.x += v.x; g.y += v.y; g.z += v.z; g.w += v.w;
    }
    float f15 = 1.5f * ic, f05 = -0.5f * ic * ic, nh = -0.5f * ic;
    float4 y;
    y.x = f15 * a.x + f05 * g.x; y.y = f15 * a.y + f05 * g.y;
    y.z = f15 * a.z + f05 * g.z; y.w = f15 * a.w + f05 * g.w;
    *(float4*)(Yb + (long long)r * sYZ + idx) = y;
    float4 z;
    z.x = nh * a.x; z.y = nh * a.y; z.z = nh * a.z; z.w = nh * a.w;
    int dq = row - col;
    if (dq >= 0 && dq < 4) (&z.x)[dq] += 1.5f;
    *(float4*)(Zb + (long long)r * sYZ + idx) = z;
}

// bias_j = mu_b[j] - sum_k mu_c[k]*M[j][k]
__global__ __launch_bounds__(64) void bias_kernel(const float* __restrict__ M,
                                                  const float* __restrict__ means,
                                                  float* __restrict__ bias) {
    int j = blockIdx.x;
    int lane = threadIdx.x;
    const float* mu_c = means;
    const float* mu_b = means + 2 * DD;
    float p = 0.f;
    for (int k = lane; k < DD; k += 64)
        p += mu_c[k] * M[(long)j * DD + k];
    #pragma unroll
    for (int off = 32; off > 0; off >>= 1)
        p += __shfl_down(p, off, 64);
    if (lane == 0) bias[j] = mu_b[j] - p;
}

// out = X @ M^T + bias; 128x128 tiles, 8x8 micro.
__global__ __launch_bounds__(256) void outgemm2_kernel(const float* __restrict__ X,
                                                       const float* __restrict__ M,
                                                       const float* __restrict__ bias,
                                                       float* __restrict__ out) {
    int j0 = blockIdx.x << 7;
    int i0 = blockIdx.y << 7;
    __shared__ float As[32][132];
    __shared__ float Bs[32][140];
    int t = threadIdx.x;
    int iy = t >> 4, ix = t & 15;
    int ldr = t >> 3;
    int ldc = (t & 7) << 2;
    int boff = (ix << 3) + ((ix >> 2) << 2);
    float acc[8][8] = {};
    float4 pa[4], pb[4];
    #pragma unroll
    for (int p = 0; p < 4; ++p) {
        pa[p] = *(const float4*)(X + (long)(i0 + ldr + p * 32) * DD + ldc);
        pb[p] = *(const float4*)(M + (long)(j0 + ldr + p * 32) * DD + ldc);
    }
    for (int kb = 0; kb < DD; kb += 32) {
        __syncthreads();
        #pragma unroll
        for (int p = 0; p < 4; ++p) {
            int r = ldr + p * 32;
            As[ldc + 0][r] = pa[p].x; As[ldc + 1][r] = pa[p].y;
            As[ldc + 2][r] = pa[p].z; As[ldc + 3][r] = pa[p].w;
            int q = r >> 2;
            int bc = (q << 2) + ((q >> 3) << 2) + (r & 3);
            Bs[ldc + 0][bc] = pb[p].x; Bs[ldc + 1][bc] = pb[p].y;
            Bs[ldc + 2][bc] = pb[p].z; Bs[ldc + 3][bc] = pb[p].w;
        }
        __syncthreads();
        if (kb + 32 < DD) {
            #pragma unroll
            for (int p = 0; p < 4; ++p) {
                pa[p] = *(const float4*)(X + (long)(i0 + ldr + p * 32) * DD + kb + 32 + ldc);
                pb[p] = *(const float4*)(M + (long)(j0 + ldr + p * 32) * DD + kb + 32 + ldc);
            }
        }
        #pragma unroll 4
        for (int kk = 0; kk < 32; ++kk) {
            float a[8], bf[8];
            *(float4*)&a[0] = *(const float4*)&As[kk][iy << 3];
            *(float4*)&a[4] = *(const float4*)&As[kk][(iy << 3) + 4];
            *(float4*)&bf[0] = *(const float4*)&Bs[kk][boff];
            *(float4*)&bf[4] = *(const float4*)&Bs[kk][boff + 4];
            #pragma unroll
            for (int i = 0; i < 8; ++i)
                #pragma unroll
                for (int j = 0; j < 8; ++j)
                    acc[i][j] += a[i] * bf[j];
        }
    }
    float4 bv0 = *(const float4*)(bias + j0 + (ix << 3));
    float4 bv1 = *(const float4*)(bias + j0 + (ix << 3) + 4);
    #pragma unroll
    for (int i = 0; i < 8; ++i) {
        long off = (long)(i0 + (iy << 3) + i) * DD + j0 + (ix << 3);
        float4 v0 = *(float4*)&acc[i][0];
        float4 v1 = *(float4*)&acc[i][4];
        v0.x += bv0.x; v0.y += bv0.y; v0.z += bv0.z; v0.w += bv0.w;
        v1.x += bv1.x; v1.y += bv1.y; v1.z += bv1.z; v1.w += bv1.w;
        *(float4*)(out + off) = v0;
        *(float4*)(out + off + 4) = v1;
    }
}

// ---------------- host orchestration ----------------
extern "C" void kernel_launch(void* const* d_in, const int* in_sizes, int n_in,
                              void* d_out, int out_size, void* d_ws, size_t ws_size,
                              hipStream_t stream) {
    const float* X = (const float*)d_in[0];
    const float* S = (const float*)d_in[1];
    float* out = (float*)d_out;
    float* ws = (float*)d_ws;
    float* pool    = out;                 // 16 MB split-K partials, dead until outgemm
    float* covpool = out + 16ll * MSZ;    // 2 MB covsyrk accumulators

    // ws: [0,512) mean_c, [512,1024) mean_s, [1024,1536) mu_b, [1536,2048) bias
    //     2048..2064 trSig[17], 2068..2099 trMid[32], 2100 trMidF (+2101 zero pad)
    // MATS = ws+4096 (19 slots ~19MB, under 24MB proven):
    //   0 covc, 1 covs, 2 Sg0, 3 Sg1, 4 Y, 5 Z, 6 W, 7 P0, 8 P1,
    //   9 mid0, 10 mid1, 11 U, 12 M, 13 Yb0, 14 Yb1, 15 Zb0, 16 Zb1, 17 Wb0, 18 Wb1
    float* trSig  = ws + 2048;
    float* trMid  = ws + 2068;
    float* trMidF = ws + 2100;
    float* bias   = ws + 1536;
    float* MATS   = ws + 4096;
    auto m_ = [&](int i) { return MATS + (long long)i * MSZ; };
    float* covc = m_(0);
    float* Sg[2] = { m_(2), m_(3) };
    float* Y = m_(4);
    float* Z = m_(5);
    float* W = m_(6);
    float* P01 = m_(7);
    float* mid01 = m_(9);
    float* U = m_(11);
    float* Mx = m_(12);
    float* Yb = m_(13);   // nb=2 layout: Y 13,14 | Z 15,16 | W 17,18

    hipMemsetAsync(ws, 0, 4096 * sizeof(float), stream);             // means + traces
    hipMemsetAsync(covpool, 0, 2ll * MSZ * sizeof(float), stream);   // covsyrk accumulators

    colsum_kernel<<<dim3(256, 2), 512, 0, stream>>>(X, S, ws);
    finalize_mean_kernel<<<1, 512, 0, stream>>>(ws);
    covsyrk2_kernel<<<dim3(16, CSPLIT, 2), 256, 0, stream>>>(X, S, covpool);
    covfix_kernel<<<dim3(512, 2), 512, 0, stream>>>(covpool, covc, ws, trSig);

    // gemm to pool; aop/bop select the operand transform
    auto MM = [&](int aop, int bop, int batch,
                  const float* A1, long long sA1, const float* A2, long long sA2, int asplit,
                  const float* B1, long long sB1, const float* B2, long long sB2, int bsplit,
                  const float* qslot, float hq1, float hq2) {
        dim3 g(32, 16 / batch, batch);
        if (aop == 1)
            mmk<1, 1><<<g, 256, 0, stream>>>(A1, A2, sA1, sA2, asplit, B1, B2, sB1, sB2, bsplit,
                                             qslot, hq1, hq2, pool);
        else if (bop == 1)
            mmk<0, 1><<<g, 256, 0, stream>>>(A1, A2, sA1, sA2, asplit, B1, B2, sB1, sB2, bsplit,
                                             qslot, hq1, hq2, pool);
        else if (bop == 2)
            mmk<0, 2><<<g, 256, 0, stream>>>(A1, A2, sA1, sA2, asplit, B1, B2, sB1, sB2, bsplit,
                                             qslot, hq1, hq2, pool);
        else
            mmk<0, 0><<<g, 256, 0, stream>>>(A1, A2, sA1, sA2, asplit, B1, B2, sB1, sB2, bsplit,
                                             qslot, hq1, hq2, pool);
    };
    auto RED = [&](int batch,
                   const float* D1, const float* D2, long long sD1, long long sD2, int dsplit,
                   float* C1, float* C2, long long sC1, long long sC2, int csplit,
                   float alpha, float beta, const float* aslot, int amode,
                   float* trout, long long strout) {
        dim3 g(256, batch);
        if (batch == 1)
            reducek<16><<<g, 256, 0, stream>>>(pool, D1, D2, sD1, sD2, dsplit, C1, C2, sC1, sC2,
                                               csplit, alpha, beta, aslot, amode, trout, strout);
        else if (batch == 2)
            reducek<8><<<g, 256, 0, stream>>>(pool, D1, D2, sD1, sD2, dsplit, C1, C2, sC1, sC2,
                                              csplit, alpha, beta, aslot, amode, trout, strout);
        else
            reducek<4><<<g, 256, 0, stream>>>(pool, D1, D2, sD1, sD2, dsplit, C1, C2, sC1, sC2,
                                              csplit, alpha, beta, aslot, amode, trout, strout);
    };
    auto NSI = [&](int nb, const float* A, long long sA, int symA,
                   float* Yo, float* Zo, long long sYZ, const float* trb, int trstride) {
        dim3 g(256, nb);
        if (nb == 1)
            nsinitk<16><<<g, 256, 0, stream>>>(pool, A, sA, symA, Yo, Zo, sYZ, trb, trstride);
        else
            nsinitk<8><<<g, 256, 0, stream>>>(pool, A, sA, symA, Yo, Zo, sYZ, trb, trstride);
    };
    // NS tail loop; requires layout Z = Ybase + nb*MSZ, W = Ybase + 2nb*MSZ (stride MSZ)
    auto NSLOOP = [&](float* Yx, int nb, int iters) {
        float* Zx = Yx + (long long)nb * MSZ;
        float* Wx = Yx + 2ll * nb * MSZ;
        for (int k = 0; k < iters; ++k) {
            MM(0, 0, nb, Zx, MSZ, nullptr, 0, nb, Yx, MSZ, nullptr, 0, nb, nullptr, 0.f, 0.f);
            RED(nb, nullptr, nullptr, 0, 0, nb, Wx, nullptr, MSZ, 0, nb,
                1.f, 0.f, nullptr, 0, nullptr, 0);
            // batch 2nb: b<nb: Y_b = 1.5Y_b - 0.5*W_b@Y_b ; b>=nb: Z_b = 1.5Z_b - 0.5*W_b@Z_b
            MM(0, 0, 2 * nb, Wx, MSZ, Wx, MSZ, nb, Yx, MSZ, nullptr, 0, 2 * nb, nullptr, 0.f, 0.f);
            RED(2 * nb, Yx, nullptr, MSZ, 0, 2 * nb, Yx, nullptr, MSZ, 0, 2 * nb,
                -0.5f, 1.5f, nullptr, 0, nullptr, 0);
        }
    };

    for (int t = 0; t < BARY_ITERS; ++t) {
        const float* Sread = (t == 0) ? covc : Sg[(t + 1) & 1];
        float* Snxt = Sg[t & 1];
        // Sigma NS (4 total iters): G = sym(S)@sym(S) -> fused init -> 3 loop
        MM(1, 1, 1, Sread, 0, nullptr, 0, 1, Sread, 0, nullptr, 0, 1, nullptr, 0.f, 0.f);
        NSI(1, Sread, 0, 1, Y, Z, MSZ, trSig + t, 0);
        NSLOOP(Y, 1, NS_SIG);
        // P_j = Ysig @ cov_j (batch 2)
        MM(0, 0, 2, Y, 0, nullptr, 0, 2, covc, MSZ, nullptr, 0, 2, nullptr, 0.f, 0.f);
        RED(2, nullptr, nullptr, 0, 0, 2, P01, nullptr, MSZ, 0, 2, 1.f, 0.f, nullptr, 0, nullptr, 0);
        // mid_j = c0 * P_j @ Ysig (+ traces)
        MM(0, 0, 2, P01, MSZ, nullptr, 0, 2, Y, 0, nullptr, 0, 2, nullptr, 0.f, 0.f);
        RED(2, nullptr, nullptr, 0, 0, 2, mid01, nullptr, MSZ, 0, 2,
            1.f, 0.f, trSig + t, 1, trMid + 2 * t, 1);
        // mid NS (5 total iters), nb=2 in slots 13..18
        MM(0, 0, 2, mid01, MSZ, nullptr, 0, 2, mid01, MSZ, nullptr, 0, 2, nullptr, 0.f, 0.f);
        NSI(2, mid01, MSZ, 0, Yb, Yb + 2ll * MSZ, MSZ, trMid + 2 * t, 1);
        NSLOOP(Yb, 2, NS_MID);
        // U = Zsig @ (0.5*sqrt(c1)*Yb0 + 0.5*sqrt(c2)*Yb1)
        MM(0, 2, 1, Z, 0, nullptr, 0, 1, Yb, 0, Yb + MSZ, 0, 1, trMid + 2 * t, 0.5f, 0.5f);
        RED(1, nullptr, nullptr, 0, 0, 1, U, nullptr, 0, 0, 1, 1.f, 0.f, nullptr, 0, nullptr, 0);
        // Snxt = (1/c0) * U @ Zsig (+ trace for next iter); symmetrized on load next iter
        MM(0, 0, 1, U, 0, nullptr, 0, 1, Z, 0, nullptr, 0, 1, nullptr, 0.f, 0.f);
        RED(1, nullptr, nullptr, 0, 0, 1, Snxt, nullptr, 0, 0, 1,
            1.f, 0.f, trSig + t, 2, trSig + t + 1, 0);
    }

    // ---- final: M = covc^{-1/2} (covc^{1/2} Sigma covc^{1/2})^{1/2} covc^{-1/2} ----
    const float* SigF = Sg[1];   // written at t=15
    MM(1, 1, 1, covc, 0, nullptr, 0, 1, covc, 0, nullptr, 0, 1, nullptr, 0.f, 0.f);
    NSI(1, covc, 0, 1, Y, Z, MSZ, trSig, 0);
    NSLOOP(Y, 1, NS_SIG);
    // P = Ysig @ sym(SigF)
    MM(0, 1, 1, Y, 0, nullptr, 0, 1, SigF, 0, nullptr, 0, 1, nullptr, 0.f, 0.f);
    RED(1, nullptr, nullptr, 0, 0, 1, P01, nullptr, 0, 0, 1, 1.f, 0.f, nullptr, 0, nullptr, 0);
    // midF = c0 * P @ Ysig (+ trace)
    MM(0, 0, 1, P01, 0, nullptr, 0, 1, Y, 0, nullptr, 0, 1, nullptr, 0.f, 0.f);
    RED(1, nullptr, nullptr, 0, 0, 1, mid01, nullptr, 0, 0, 1,
        1.f, 0.f, trSig, 1, trMidF, 0);
    // mid NS (5 total), nb=1 in slots 13,14,15
    MM(0, 0, 1, mid01, 0, nullptr, 0, 1, mid01, 0, nullptr, 0, 1, nullptr, 0.f, 0.f);
    NSI(1, mid01, 0, 0, Yb, Yb + MSZ, MSZ, trMidF, 0);
    NSLOOP(Yb, 1, NS_MID);
    // U = sqrt(c1) * Zsig @ Yb
    MM(0, 2, 1, Z, 0, nullptr, 0, 1, Yb, 0, Yb, 0, 1, trMidF, 1.f, 0.f);
    RED(1, nullptr, nullptr, 0, 0, 1, U, nullptr, 0, 0, 1, 1.f, 0.f, nullptr, 0, nullptr, 0);
    // M = (1/c0) * U @ Zsig
    MM(0, 0, 1, U, 0, nullptr, 0, 1, Z, 0, nullptr, 0, 1, nullptr, 0.f, 0.f);
    RED(1, nullptr, nullptr, 0, 0, 1, Mx, nullptr, 0, 0, 1, 1.f, 0.f, trSig, 2, nullptr, 0);

    bias_kernel<<<512, 64, 0, stream>>>(Mx, ws, bias);
    outgemm2_kernel<<<dim3(4, 512), 256, 0, stream>>>(X, Mx, bias, out);
}